// Round 1
// baseline (3912.157 us; speedup 1.0000x reference)
//
#include <hip/hip_runtime.h>
#include <math.h>

// GCN 3-layer forward: h = relu(gcnconv(x)) x2, then gcnconv -> log_softmax.
// gcnconv: deg-normalized scatter-add with self-loops: out = D^-1/2 A D^-1/2 (xW) + b

static inline size_t align256(size_t x) { return (x + 255) & ~(size_t)255; }

// ---------- degree / norm ----------
__global__ void k_deg_init(int* __restrict__ deg, int n) {
    int i = blockIdx.x * blockDim.x + threadIdx.x;
    if (i < n) deg[i] = 1;   // self-loop
}

__global__ void k_deg_count(const int* __restrict__ dst, int* __restrict__ deg, int e) {
    int i = blockIdx.x * blockDim.x + threadIdx.x;
    if (i < e) atomicAdd(&deg[dst[i]], 1);
}

__global__ void k_dis(const int* __restrict__ deg, float* __restrict__ dis, int n) {
    int i = blockIdx.x * blockDim.x + threadIdx.x;
    if (i < n) dis[i] = rsqrtf((float)deg[i]);
}

// ---------- dense GEMM: H[n,DOUT] = act(X[n,64]) @ W[64,DOUT] ----------
template<int DOUT, bool RELU_IN>
__global__ void k_gemm(const float* __restrict__ X, const float* __restrict__ W,
                       float* __restrict__ H, int n) {
    __shared__ __align__(16) float Ws[64 * DOUT];
    for (int i = threadIdx.x; i < 64 * DOUT; i += blockDim.x) Ws[i] = W[i];
    __syncthreads();
    int row = blockIdx.x * blockDim.x + threadIdx.x;
    if (row >= n) return;
    float4 acc[DOUT / 4];
    #pragma unroll
    for (int j = 0; j < DOUT / 4; ++j) acc[j] = make_float4(0.f, 0.f, 0.f, 0.f);
    const float4* xr = (const float4*)(X + (size_t)row * 64);
    #pragma unroll
    for (int k4 = 0; k4 < 16; ++k4) {
        float4 xv = xr[k4];
        float xs[4];
        xs[0] = xv.x; xs[1] = xv.y; xs[2] = xv.z; xs[3] = xv.w;
        #pragma unroll
        for (int kk = 0; kk < 4; ++kk) {
            float xv1 = RELU_IN ? fmaxf(xs[kk], 0.f) : xs[kk];
            const float4* wr = (const float4*)&Ws[(k4 * 4 + kk) * DOUT];
            #pragma unroll
            for (int j = 0; j < DOUT / 4; ++j) {
                float4 wv = wr[j];
                acc[j].x += xv1 * wv.x;
                acc[j].y += xv1 * wv.y;
                acc[j].z += xv1 * wv.z;
                acc[j].w += xv1 * wv.w;
            }
        }
    }
    float4* hr = (float4*)(H + (size_t)row * DOUT);
    #pragma unroll
    for (int j = 0; j < DOUT / 4; ++j) hr[j] = acc[j];
}

// ---------- self-loop + bias init: AGG[i] = H[i]*dis[i]^2 + b ----------
template<int DOUT>
__global__ void k_selfloop_bias(const float* __restrict__ H, const float* __restrict__ dis,
                                const float* __restrict__ b, float* __restrict__ AGG, int n) {
    const int CP4 = DOUT / 4;
    int tid = blockIdx.x * blockDim.x + threadIdx.x;
    int i = tid / CP4, c = tid - i * CP4;
    if (i >= n) return;
    float d = dis[i];
    float d2 = d * d;
    float4 v = *(const float4*)(H + (size_t)i * DOUT + c * 4);
    float4 bb = *(const float4*)(b + c * 4);
    float4 o;
    o.x = v.x * d2 + bb.x;
    o.y = v.y * d2 + bb.y;
    o.z = v.z * d2 + bb.z;
    o.w = v.w * d2 + bb.w;
    *(float4*)(AGG + (size_t)i * DOUT + c * 4) = o;
}

// ---------- edge scatter: AGG[dst] += H[src] * dis[src]*dis[dst] ----------
template<int DOUT>
__global__ void k_scatter(const int* __restrict__ src, const int* __restrict__ dst,
                          const float* __restrict__ dis, const float* __restrict__ H,
                          float* __restrict__ AGG, int e) {
    const int CP4 = DOUT / 4;
    int tid = blockIdx.x * blockDim.x + threadIdx.x;
    int ei = tid / CP4, c = tid - ei * CP4;
    if (ei >= e) return;
    int s = src[ei], d = dst[ei];
    float nrm = dis[s] * dis[d];
    float4 v = *(const float4*)(H + (size_t)s * DOUT + c * 4);
    float* o = AGG + (size_t)d * DOUT + c * 4;
    unsafeAtomicAdd(o + 0, v.x * nrm);
    unsafeAtomicAdd(o + 1, v.y * nrm);
    unsafeAtomicAdd(o + 2, v.z * nrm);
    unsafeAtomicAdd(o + 3, v.w * nrm);
}

// ---------- log_softmax over 40 channels, one wave per node ----------
__global__ void k_logsoftmax(float* __restrict__ out, int n) {
    int gid = blockIdx.x * blockDim.x + threadIdx.x;
    int node = gid >> 6, lane = threadIdx.x & 63;
    if (node >= n) return;
    float* row = out + (size_t)node * 40;
    float v = (lane < 40) ? row[lane] : -INFINITY;
    float m = v;
    #pragma unroll
    for (int off = 32; off >= 1; off >>= 1) m = fmaxf(m, __shfl_xor(m, off, 64));
    float ex = (lane < 40) ? __expf(v - m) : 0.f;
    float s = ex;
    #pragma unroll
    for (int off = 32; off >= 1; off >>= 1) s += __shfl_xor(s, off, 64);
    if (lane < 40) row[lane] = v - m - __logf(s);
}

extern "C" void kernel_launch(void* const* d_in, const int* in_sizes, int n_in,
                              void* d_out, int out_size, void* d_ws, size_t ws_size,
                              hipStream_t stream) {
    const float* x  = (const float*)d_in[0];
    const int*   ei = (const int*)d_in[1];
    const float* W1 = (const float*)d_in[2];
    const float* b1 = (const float*)d_in[3];
    const float* W2 = (const float*)d_in[4];
    const float* b2 = (const float*)d_in[5];
    const float* W3 = (const float*)d_in[6];
    const float* b3 = (const float*)d_in[7];
    float* out = (float*)d_out;

    const int N = in_sizes[0] / 64;
    const int E = in_sizes[1] / 2;
    const int* src = ei;
    const int* dst = ei + E;

    // workspace layout
    char* ws = (char*)d_ws;
    size_t off = 0;
    int*   deg = (int*)(ws + off);   off = align256(off + (size_t)N * 4);
    float* dis = (float*)(ws + off); off = align256(off + (size_t)N * 4);
    float* h   = (float*)(ws + off); off = align256(off + (size_t)N * 64 * 4);
    float* agg = (float*)(ws + off); off = align256(off + (size_t)N * 64 * 4);
    (void)ws_size; (void)n_in; (void)out_size;

    const int B = 256;
    auto cdiv = [](long a, long b) { return (int)((a + b - 1) / b); };

    // degree + rsqrt (once, reused by all 3 layers)
    k_deg_init<<<cdiv(N, B), B, 0, stream>>>(deg, N);
    k_deg_count<<<cdiv(E, B), B, 0, stream>>>(dst, deg, E);
    k_dis<<<cdiv(N, B), B, 0, stream>>>(deg, dis, N);

    // ---- layer 1: x -> agg ----
    k_gemm<64, false><<<cdiv(N, B), B, 0, stream>>>(x, W1, h, N);
    k_selfloop_bias<64><<<cdiv((long)N * 16, B), B, 0, stream>>>(h, dis, b1, agg, N);
    k_scatter<64><<<cdiv((long)E * 16, B), B, 0, stream>>>(src, dst, dis, h, agg, E);

    // ---- layer 2: relu(agg) -> agg ----
    k_gemm<64, true><<<cdiv(N, B), B, 0, stream>>>(agg, W2, h, N);
    k_selfloop_bias<64><<<cdiv((long)N * 16, B), B, 0, stream>>>(h, dis, b2, agg, N);
    k_scatter<64><<<cdiv((long)E * 16, B), B, 0, stream>>>(src, dst, dis, h, agg, E);

    // ---- layer 3: relu(agg) -> out (40 ch) ----
    k_gemm<40, true><<<cdiv(N, B), B, 0, stream>>>(agg, W3, h, N);
    k_selfloop_bias<40><<<cdiv((long)N * 10, B), B, 0, stream>>>(h, dis, b3, out, N);
    k_scatter<40><<<cdiv((long)E * 10, B), B, 0, stream>>>(src, dst, dis, h, out, E);

    // ---- log_softmax in place on out ----
    k_logsoftmax<<<cdiv((long)N * 64, B), B, 0, stream>>>(out, N);
}

// Round 2
// 539.933 us; speedup vs baseline: 7.2456x; 7.2456x over previous
//
#include <hip/hip_runtime.h>
#include <math.h>

// GCN 3-layer forward, CSR-gather formulation (no fp32 atomics).
// out[i] = dis[i]*(hs[i] + sum_{src in N(i)} hs[src]) + b,  hs = (act(X)@W)*dis[row]

static inline size_t align256(size_t x) { return (x + 255) & ~(size_t)255; }

// ---------- degree / norm / CSR build ----------
__global__ void k_deg_init(int* __restrict__ deg, int* __restrict__ counter, int n) {
    int i = blockIdx.x * blockDim.x + threadIdx.x;
    if (i < n) deg[i] = 0;
    if (i == 0) *counter = 0;
}

__global__ void k_deg_count(const int* __restrict__ dst, int* __restrict__ deg, int e) {
    int i = blockIdx.x * blockDim.x + threadIdx.x;
    if (i < e) atomicAdd(&deg[dst[i]], 1);
}

__global__ void k_dis(const int* __restrict__ deg, float* __restrict__ dis, int n) {
    int i = blockIdx.x * blockDim.x + threadIdx.x;
    if (i < n) dis[i] = rsqrtf((float)(deg[i] + 1));  // +1 self-loop
}

// cursor[i] = segment start for node i (any disjoint contiguous assignment works)
__global__ void k_start(const int* __restrict__ deg, int* __restrict__ cursor,
                        int* __restrict__ counter, int n) {
    int i = blockIdx.x * blockDim.x + threadIdx.x;
    if (i < n) cursor[i] = atomicAdd(counter, deg[i]);
}

__global__ void k_fill(const int* __restrict__ src, const int* __restrict__ dst,
                       int* __restrict__ cursor, int* __restrict__ eidx, int e) {
    int i = blockIdx.x * blockDim.x + threadIdx.x;
    if (i < e) {
        int pos = atomicAdd(&cursor[dst[i]], 1);
        eidx[pos] = src[i];
    }
}
// after k_fill, cursor[i] == segment END for node i; start = end - deg.

// ---------- dense GEMM: HS[n,DOUT] = (act(X[n,64]) @ W[64,DOUT]) * dis[row] ----------
template<int DOUT, bool RELU_IN>
__global__ void k_gemm(const float* __restrict__ X, const float* __restrict__ W,
                       const float* __restrict__ dis, float* __restrict__ HS, int n) {
    __shared__ __align__(16) float Ws[64 * DOUT];
    for (int i = threadIdx.x; i < 64 * DOUT; i += blockDim.x) Ws[i] = W[i];
    __syncthreads();
    int row = blockIdx.x * blockDim.x + threadIdx.x;
    if (row >= n) return;
    float4 acc[DOUT / 4];
    #pragma unroll
    for (int j = 0; j < DOUT / 4; ++j) acc[j] = make_float4(0.f, 0.f, 0.f, 0.f);
    const float4* xr = (const float4*)(X + (size_t)row * 64);
    #pragma unroll
    for (int k4 = 0; k4 < 16; ++k4) {
        float4 xv = xr[k4];
        float xs[4];
        xs[0] = xv.x; xs[1] = xv.y; xs[2] = xv.z; xs[3] = xv.w;
        #pragma unroll
        for (int kk = 0; kk < 4; ++kk) {
            float xv1 = RELU_IN ? fmaxf(xs[kk], 0.f) : xs[kk];
            const float4* wr = (const float4*)&Ws[(k4 * 4 + kk) * DOUT];
            #pragma unroll
            for (int j = 0; j < DOUT / 4; ++j) {
                float4 wv = wr[j];
                acc[j].x += xv1 * wv.x;
                acc[j].y += xv1 * wv.y;
                acc[j].z += xv1 * wv.z;
                acc[j].w += xv1 * wv.w;
            }
        }
    }
    float ds = dis[row];
    float4* hr = (float4*)(HS + (size_t)row * DOUT);
    #pragma unroll
    for (int j = 0; j < DOUT / 4; ++j) {
        acc[j].x *= ds; acc[j].y *= ds; acc[j].z *= ds; acc[j].w *= ds;
        hr[j] = acc[j];
    }
}

// ---------- gather: one wave per node, lane = channel ----------
template<int DOUT>
__global__ void k_gather(const int* __restrict__ end_cursor, const int* __restrict__ deg,
                         const int* __restrict__ eidx, const float* __restrict__ hs,
                         const float* __restrict__ dis, const float* __restrict__ b,
                         float* __restrict__ out, int n) {
    int node = (blockIdx.x * blockDim.x + threadIdx.x) >> 6;
    int lane = threadIdx.x & 63;
    if (node >= n) return;
    int d = deg[node];
    int s0 = end_cursor[node] - d;
    const int* ep = eidx + s0;
    float acc = 0.f;
    if (lane < DOUT) acc = hs[(size_t)node * DOUT + lane];  // self-loop term
    int k = 0;
    for (; k + 4 <= d; k += 4) {
        int i0 = ep[k], i1 = ep[k + 1], i2 = ep[k + 2], i3 = ep[k + 3];
        if (lane < DOUT) {
            float v0 = hs[(size_t)i0 * DOUT + lane];
            float v1 = hs[(size_t)i1 * DOUT + lane];
            float v2 = hs[(size_t)i2 * DOUT + lane];
            float v3 = hs[(size_t)i3 * DOUT + lane];
            acc += v0; acc += v1; acc += v2; acc += v3;
        }
    }
    for (; k < d; ++k) {
        int i0 = ep[k];
        if (lane < DOUT) acc += hs[(size_t)i0 * DOUT + lane];
    }
    if (lane < DOUT) out[(size_t)node * DOUT + lane] = acc * dis[node] + b[lane];
}

// ---------- log_softmax over 40 channels, one wave per node ----------
__global__ void k_logsoftmax(float* __restrict__ out, int n) {
    int gid = blockIdx.x * blockDim.x + threadIdx.x;
    int node = gid >> 6, lane = threadIdx.x & 63;
    if (node >= n) return;
    float* row = out + (size_t)node * 40;
    float v = (lane < 40) ? row[lane] : -INFINITY;
    float m = v;
    #pragma unroll
    for (int off = 32; off >= 1; off >>= 1) m = fmaxf(m, __shfl_xor(m, off, 64));
    float ex = (lane < 40) ? __expf(v - m) : 0.f;
    float s = ex;
    #pragma unroll
    for (int off = 32; off >= 1; off >>= 1) s += __shfl_xor(s, off, 64);
    if (lane < 40) row[lane] = v - m - __logf(s);
}

extern "C" void kernel_launch(void* const* d_in, const int* in_sizes, int n_in,
                              void* d_out, int out_size, void* d_ws, size_t ws_size,
                              hipStream_t stream) {
    const float* x  = (const float*)d_in[0];
    const int*   ei = (const int*)d_in[1];
    const float* W1 = (const float*)d_in[2];
    const float* b1 = (const float*)d_in[3];
    const float* W2 = (const float*)d_in[4];
    const float* b2 = (const float*)d_in[5];
    const float* W3 = (const float*)d_in[6];
    const float* b3 = (const float*)d_in[7];
    float* out = (float*)d_out;

    const int N = in_sizes[0] / 64;
    const int E = in_sizes[1] / 2;
    const int* src = ei;
    const int* dst = ei + E;

    // workspace layout
    char* ws = (char*)d_ws;
    size_t off = 0;
    int*   deg     = (int*)(ws + off);   off = align256(off + (size_t)N * 4);
    float* dis     = (float*)(ws + off); off = align256(off + (size_t)N * 4);
    int*   cursor  = (int*)(ws + off);   off = align256(off + (size_t)N * 4);
    int*   counter = (int*)(ws + off);   off = align256(off + 256);
    int*   eidx    = (int*)(ws + off);   off = align256(off + (size_t)E * 4);
    float* hs      = (float*)(ws + off); off = align256(off + (size_t)N * 64 * 4);
    float* agg     = (float*)(ws + off); off = align256(off + (size_t)N * 64 * 4);
    (void)ws_size; (void)n_in; (void)out_size;

    const int B = 256;
    auto cdiv = [](long a, long b) { return (int)((a + b - 1) / b); };

    // ---- CSR build (once per call, reused by all 3 layers) ----
    k_deg_init<<<cdiv(N, B), B, 0, stream>>>(deg, counter, N);
    k_deg_count<<<cdiv(E, B), B, 0, stream>>>(dst, deg, E);
    k_dis<<<cdiv(N, B), B, 0, stream>>>(deg, dis, N);
    k_start<<<cdiv(N, B), B, 0, stream>>>(deg, cursor, counter, N);
    k_fill<<<cdiv(E, B), B, 0, stream>>>(src, dst, cursor, eidx, E);

    // ---- layer 1: x -> agg ----
    k_gemm<64, false><<<cdiv(N, B), B, 0, stream>>>(x, W1, dis, hs, N);
    k_gather<64><<<cdiv((long)N * 64, B), B, 0, stream>>>(cursor, deg, eidx, hs, dis, b1, agg, N);

    // ---- layer 2: relu(agg) -> agg ----
    k_gemm<64, true><<<cdiv(N, B), B, 0, stream>>>(agg, W2, dis, hs, N);
    k_gather<64><<<cdiv((long)N * 64, B), B, 0, stream>>>(cursor, deg, eidx, hs, dis, b2, agg, N);

    // ---- layer 3: relu(agg) -> out (40 ch) ----
    k_gemm<40, true><<<cdiv(N, B), B, 0, stream>>>(agg, W3, dis, hs, N);
    k_gather<40><<<cdiv((long)N * 64, B), B, 0, stream>>>(cursor, deg, eidx, hs, dis, b3, out, N);

    // ---- log_softmax in place on out ----
    k_logsoftmax<<<cdiv((long)N * 64, B), B, 0, stream>>>(out, N);
}

// Round 3
// 414.097 us; speedup vs baseline: 9.4474x; 1.3039x over previous
//
#include <hip/hip_runtime.h>
#include <math.h>

// GCN 3-layer forward, CSR-gather formulation.
// CSR built via atomic-free bucketed counting sort (bucket = dst>>8).
// out[i] = dis[i]*(hs[i] + sum_{src in N(i)} hs[src]) + b,  hs = (act(X)@W)*dis[row]

static inline size_t align256(size_t x) { return (x + 255) & ~(size_t)255; }

#define NBLK 128          // blocks for hist/bucket passes
#define MAXB 6144         // max edges per bucket staged in LDS (mean 4096, +32 sigma)

// ---------- pass 1: per-block bucket histogram ----------
__global__ void k_hist(const int* __restrict__ dst, int* __restrict__ blockHist,
                       int e, int nb, int chunk) {
    __shared__ int h[512];
    for (int i = threadIdx.x; i < nb; i += blockDim.x) h[i] = 0;
    __syncthreads();
    int b0 = blockIdx.x * chunk, b1 = min(b0 + chunk, e);
    for (int i = b0 + threadIdx.x; i < b1; i += blockDim.x)
        atomicAdd(&h[dst[i] >> 8], 1);
    __syncthreads();
    for (int i = threadIdx.x; i < nb; i += blockDim.x)
        blockHist[blockIdx.x * nb + i] = h[i];
}

// ---------- pass 2: offsets (1 block, 512 threads) ----------
__global__ void k_scan(const int* __restrict__ blockHist, int* __restrict__ blockOff,
                       int* __restrict__ bucketBase, int* __restrict__ rowptr,
                       int nblk, int nb, int e, int n) {
    __shared__ int tot[512];
    __shared__ int wsum[8];
    int k = threadIdx.x;
    int s = 0;
    if (k < nb) {
        for (int b = 0; b < nblk; ++b) {
            int t = blockHist[b * nb + k];
            blockOff[b * nb + k] = s;
            s += t;
        }
    }
    tot[k] = (k < nb) ? s : 0;
    __syncthreads();
    int dv = tot[k];
    int v = dv;
    int lane = k & 63, w = k >> 6;
    #pragma unroll
    for (int off = 1; off < 64; off <<= 1) {
        int u = __shfl_up(v, off, 64);
        if (lane >= off) v += u;
    }
    if (lane == 63) wsum[w] = v;
    __syncthreads();
    if (k == 0) {
        int acc = 0;
        #pragma unroll
        for (int i = 0; i < 8; ++i) { int t = wsum[i]; wsum[i] = acc; acc += t; }
    }
    __syncthreads();
    int excl = v - dv + wsum[w];
    if (k < nb) bucketBase[k] = excl;
    if (k == 0) { bucketBase[nb] = e; rowptr[n] = e; }
}

// ---------- pass 3: scatter edges into bucket-sorted packed array ----------
__global__ void k_bucket(const int* __restrict__ src, const int* __restrict__ dst,
                         const int* __restrict__ blockOff, const int* __restrict__ bucketBase,
                         int* __restrict__ sorted, int e, int nb, int chunk) {
    __shared__ int cur[512];
    for (int i = threadIdx.x; i < nb; i += blockDim.x)
        cur[i] = blockOff[blockIdx.x * nb + i] + bucketBase[i];
    __syncthreads();
    int b0 = blockIdx.x * chunk, b1 = min(b0 + chunk, e);
    for (int i = b0 + threadIdx.x; i < b1; i += blockDim.x) {
        int d = dst[i];
        int pos = atomicAdd(&cur[d >> 8], 1);
        sorted[pos] = src[i] | ((d & 255) << 17);   // src < 2^17, dlow 8 bits
    }
}

// ---------- pass 4: per-bucket CSR finalize (1 block per bucket) ----------
__global__ void k_csr(const int* __restrict__ bucketBase, const int* __restrict__ sorted,
                      int* __restrict__ eidx, int* __restrict__ rowptr,
                      float* __restrict__ dis, int n) {
    __shared__ int pk[MAXB];
    __shared__ int deg[256];
    __shared__ int cur[256];
    __shared__ int wsum[4];
    int k = blockIdx.x;
    int base = bucketBase[k], end = bucketBase[k + 1];
    int m = end - base;
    int t = threadIdx.x;
    deg[t] = 0;
    __syncthreads();
    for (int j = t; j < m; j += 256) {
        int v = sorted[base + j];
        if (j < MAXB) pk[j] = v;
        atomicAdd(&deg[(v >> 17) & 255], 1);
    }
    __syncthreads();
    int dv = deg[t];
    int v2 = dv;
    int lane = t & 63, w = t >> 6;
    #pragma unroll
    for (int off = 1; off < 64; off <<= 1) {
        int u = __shfl_up(v2, off, 64);
        if (lane >= off) v2 += u;
    }
    if (lane == 63) wsum[w] = v2;
    __syncthreads();
    if (t == 0) {
        int acc = 0;
        #pragma unroll
        for (int i = 0; i < 4; ++i) { int x = wsum[i]; wsum[i] = acc; acc += x; }
    }
    __syncthreads();
    int excl = v2 - dv + wsum[w];
    int node = (k << 8) + t;
    if (node < n) {
        rowptr[node] = base + excl;
        dis[node] = rsqrtf((float)(dv + 1));   // +1 self-loop
    }
    cur[t] = excl;
    __syncthreads();
    for (int j = t; j < m; j += 256) {
        int v = (j < MAXB) ? pk[j] : sorted[base + j];
        int pos = atomicAdd(&cur[(v >> 17) & 255], 1);
        eidx[base + pos] = v & 0x1FFFF;
    }
}

// ---------- dense GEMM: HS[n,DOUT] = (act(X[n,64]) @ W[64,DOUT]) * dis[row] ----------
template<int DOUT, bool RELU_IN>
__global__ void k_gemm(const float* __restrict__ X, const float* __restrict__ W,
                       const float* __restrict__ dis, float* __restrict__ HS, int n) {
    __shared__ __align__(16) float Ws[64 * DOUT];
    for (int i = threadIdx.x; i < 64 * DOUT; i += blockDim.x) Ws[i] = W[i];
    __syncthreads();
    int row = blockIdx.x * blockDim.x + threadIdx.x;
    if (row >= n) return;
    float4 acc[DOUT / 4];
    #pragma unroll
    for (int j = 0; j < DOUT / 4; ++j) acc[j] = make_float4(0.f, 0.f, 0.f, 0.f);
    const float4* xr = (const float4*)(X + (size_t)row * 64);
    #pragma unroll
    for (int k4 = 0; k4 < 16; ++k4) {
        float4 xv = xr[k4];
        float xs[4];
        xs[0] = xv.x; xs[1] = xv.y; xs[2] = xv.z; xs[3] = xv.w;
        #pragma unroll
        for (int kk = 0; kk < 4; ++kk) {
            float xv1 = RELU_IN ? fmaxf(xs[kk], 0.f) : xs[kk];
            const float4* wr = (const float4*)&Ws[(k4 * 4 + kk) * DOUT];
            #pragma unroll
            for (int j = 0; j < DOUT / 4; ++j) {
                float4 wv = wr[j];
                acc[j].x += xv1 * wv.x;
                acc[j].y += xv1 * wv.y;
                acc[j].z += xv1 * wv.z;
                acc[j].w += xv1 * wv.w;
            }
        }
    }
    float ds = dis[row];
    float4* hr = (float4*)(HS + (size_t)row * DOUT);
    #pragma unroll
    for (int j = 0; j < DOUT / 4; ++j) {
        acc[j].x *= ds; acc[j].y *= ds; acc[j].z *= ds; acc[j].w *= ds;
        hr[j] = acc[j];
    }
}

// ---------- gather: one wave per node, lane = channel ----------
template<int DOUT>
__global__ void k_gather(const int* __restrict__ rowptr, const int* __restrict__ eidx,
                         const float* __restrict__ hs, const float* __restrict__ dis,
                         const float* __restrict__ b, float* __restrict__ out, int n) {
    int node = (blockIdx.x * blockDim.x + threadIdx.x) >> 6;
    int lane = threadIdx.x & 63;
    if (node >= n) return;
    int s0 = rowptr[node];
    int d = rowptr[node + 1] - s0;
    const int* ep = eidx + s0;
    float acc = 0.f;
    if (lane < DOUT) acc = hs[(size_t)node * DOUT + lane];  // self-loop term
    int k = 0;
    for (; k + 4 <= d; k += 4) {
        int i0 = ep[k], i1 = ep[k + 1], i2 = ep[k + 2], i3 = ep[k + 3];
        if (lane < DOUT) {
            float v0 = hs[(size_t)i0 * DOUT + lane];
            float v1 = hs[(size_t)i1 * DOUT + lane];
            float v2 = hs[(size_t)i2 * DOUT + lane];
            float v3 = hs[(size_t)i3 * DOUT + lane];
            acc += v0; acc += v1; acc += v2; acc += v3;
        }
    }
    for (; k < d; ++k) {
        int i0 = ep[k];
        if (lane < DOUT) acc += hs[(size_t)i0 * DOUT + lane];
    }
    if (lane < DOUT) out[(size_t)node * DOUT + lane] = acc * dis[node] + b[lane];
}

// ---------- log_softmax over 40 channels, one wave per node ----------
__global__ void k_logsoftmax(float* __restrict__ out, int n) {
    int gid = blockIdx.x * blockDim.x + threadIdx.x;
    int node = gid >> 6, lane = threadIdx.x & 63;
    if (node >= n) return;
    float* row = out + (size_t)node * 40;
    float v = (lane < 40) ? row[lane] : -INFINITY;
    float m = v;
    #pragma unroll
    for (int off = 32; off >= 1; off >>= 1) m = fmaxf(m, __shfl_xor(m, off, 64));
    float ex = (lane < 40) ? __expf(v - m) : 0.f;
    float s = ex;
    #pragma unroll
    for (int off = 32; off >= 1; off >>= 1) s += __shfl_xor(s, off, 64);
    if (lane < 40) row[lane] = v - m - __logf(s);
}

extern "C" void kernel_launch(void* const* d_in, const int* in_sizes, int n_in,
                              void* d_out, int out_size, void* d_ws, size_t ws_size,
                              hipStream_t stream) {
    const float* x  = (const float*)d_in[0];
    const int*   ei = (const int*)d_in[1];
    const float* W1 = (const float*)d_in[2];
    const float* b1 = (const float*)d_in[3];
    const float* W2 = (const float*)d_in[4];
    const float* b2 = (const float*)d_in[5];
    const float* W3 = (const float*)d_in[6];
    const float* b3 = (const float*)d_in[7];
    float* out = (float*)d_out;

    const int N = in_sizes[0] / 64;
    const int E = in_sizes[1] / 2;
    const int* src = ei;
    const int* dst = ei + E;
    const int NB = (N + 255) >> 8;          // buckets (<=512)
    const int CHUNK = (E + NBLK - 1) / NBLK;

    // workspace layout
    char* ws = (char*)d_ws;
    size_t off = 0;
    int*   rowptr     = (int*)(ws + off);   off = align256(off + (size_t)(N + 1) * 4);
    float* dis        = (float*)(ws + off); off = align256(off + (size_t)N * 4);
    int*   bucketBase = (int*)(ws + off);   off = align256(off + 2048 + 256);
    int*   eidx       = (int*)(ws + off);   off = align256(off + (size_t)E * 4);
    float* hs         = (float*)(ws + off); off = align256(off + (size_t)N * 64 * 4);
    float* agg        = (float*)(ws + off); off = align256(off + (size_t)N * 64 * 4);
    // aliases (dead before hs/agg first written):
    int*   blockHist  = (int*)hs;                     // NBLK*NB ints (<=256KB)
    int*   blockOff   = (int*)hs + (size_t)NBLK * NB; // NBLK*NB ints
    int*   sorted     = (int*)agg;                    // E ints
    (void)ws_size; (void)n_in; (void)out_size;

    const int B = 256;
    auto cdiv = [](long a, long b) { return (int)((a + b - 1) / b); };

    // ---- CSR build (atomic-free bucketed counting sort) ----
    k_hist<<<NBLK, B, 0, stream>>>(dst, blockHist, E, NB, CHUNK);
    k_scan<<<1, 512, 0, stream>>>(blockHist, blockOff, bucketBase, rowptr, NBLK, NB, E, N);
    k_bucket<<<NBLK, B, 0, stream>>>(src, dst, blockOff, bucketBase, sorted, E, NB, CHUNK);
    k_csr<<<NB, B, 0, stream>>>(bucketBase, sorted, eidx, rowptr, dis, N);

    // ---- layer 1: x -> agg ----
    k_gemm<64, false><<<cdiv(N, B), B, 0, stream>>>(x, W1, dis, hs, N);
    k_gather<64><<<cdiv((long)N * 64, B), B, 0, stream>>>(rowptr, eidx, hs, dis, b1, agg, N);

    // ---- layer 2: relu(agg) -> agg ----
    k_gemm<64, true><<<cdiv(N, B), B, 0, stream>>>(agg, W2, dis, hs, N);
    k_gather<64><<<cdiv((long)N * 64, B), B, 0, stream>>>(rowptr, eidx, hs, dis, b2, agg, N);

    // ---- layer 3: relu(agg) -> out (40 ch) ----
    k_gemm<40, true><<<cdiv(N, B), B, 0, stream>>>(agg, W3, dis, hs, N);
    k_gather<40><<<cdiv((long)N * 64, B), B, 0, stream>>>(rowptr, eidx, hs, dis, b3, out, N);

    // ---- log_softmax in place on out ----
    k_logsoftmax<<<cdiv((long)N * 64, B), B, 0, stream>>>(out, N);
}

// Round 4
// 392.179 us; speedup vs baseline: 9.9754x; 1.0559x over previous
//
#include <hip/hip_runtime.h>
#include <math.h>

// GCN 3-layer forward, CSR-gather formulation with bf16 message table.
// CSR built via atomic-free bucketed counting sort (bucket = dst>>8).
// out[i] = dis[i]*(hs[i] + sum_{src in N(i)} hs[src]) + b,  hs = (act(X)@W)*dis[row] (bf16x2-packed)

static inline size_t align256(size_t x) { return (x + 255) & ~(size_t)255; }

#define NBLK 128          // blocks for hist/bucket passes
#define MAXB 6144         // max edges per bucket staged in LDS (mean 4096, +32 sigma)

__device__ __forceinline__ unsigned short f2bf(float x) {
    union { float f; unsigned u; } v; v.f = x;
    unsigned r = v.u + 0x7fff + ((v.u >> 16) & 1);   // RNE (finite inputs)
    return (unsigned short)(r >> 16);
}
__device__ __forceinline__ float bflo(unsigned v) { union { unsigned u; float f; } t; t.u = v << 16; return t.f; }
__device__ __forceinline__ float bfhi(unsigned v) { union { unsigned u; float f; } t; t.u = v & 0xffff0000u; return t.f; }

// ---------- pass 1: per-block bucket histogram ----------
__global__ void k_hist(const int* __restrict__ dst, int* __restrict__ blockHist,
                       int e, int nb, int chunk) {
    __shared__ int h[512];
    for (int i = threadIdx.x; i < nb; i += blockDim.x) h[i] = 0;
    __syncthreads();
    int b0 = blockIdx.x * chunk, b1 = min(b0 + chunk, e);
    for (int i = b0 + threadIdx.x; i < b1; i += blockDim.x)
        atomicAdd(&h[dst[i] >> 8], 1);
    __syncthreads();
    for (int i = threadIdx.x; i < nb; i += blockDim.x)
        blockHist[blockIdx.x * nb + i] = h[i];
}

// ---------- pass 2: offsets (1 block, 512 threads) ----------
__global__ void k_scan(const int* __restrict__ blockHist, int* __restrict__ blockOff,
                       int* __restrict__ bucketBase, int* __restrict__ rowptr,
                       int nblk, int nb, int e, int n) {
    __shared__ int tot[512];
    __shared__ int wsum[8];
    int k = threadIdx.x;
    int s = 0;
    if (k < nb) {
        for (int b = 0; b < nblk; ++b) {
            int t = blockHist[b * nb + k];
            blockOff[b * nb + k] = s;
            s += t;
        }
    }
    tot[k] = (k < nb) ? s : 0;
    __syncthreads();
    int dv = tot[k];
    int v = dv;
    int lane = k & 63, w = k >> 6;
    #pragma unroll
    for (int off = 1; off < 64; off <<= 1) {
        int u = __shfl_up(v, off, 64);
        if (lane >= off) v += u;
    }
    if (lane == 63) wsum[w] = v;
    __syncthreads();
    if (k == 0) {
        int acc = 0;
        #pragma unroll
        for (int i = 0; i < 8; ++i) { int t = wsum[i]; wsum[i] = acc; acc += t; }
    }
    __syncthreads();
    int excl = v - dv + wsum[w];
    if (k < nb) bucketBase[k] = excl;
    if (k == 0) { bucketBase[nb] = e; rowptr[n] = e; }
}

// ---------- pass 3: scatter edges into bucket-sorted packed array ----------
__global__ void k_bucket(const int* __restrict__ src, const int* __restrict__ dst,
                         const int* __restrict__ blockOff, const int* __restrict__ bucketBase,
                         int* __restrict__ sorted, int e, int nb, int chunk) {
    __shared__ int cur[512];
    for (int i = threadIdx.x; i < nb; i += blockDim.x)
        cur[i] = blockOff[blockIdx.x * nb + i] + bucketBase[i];
    __syncthreads();
    int b0 = blockIdx.x * chunk, b1 = min(b0 + chunk, e);
    for (int i = b0 + threadIdx.x; i < b1; i += blockDim.x) {
        int d = dst[i];
        int pos = atomicAdd(&cur[d >> 8], 1);
        sorted[pos] = src[i] | ((d & 255) << 17);   // src < 2^17, dlow 8 bits
    }
}

// ---------- pass 4: per-bucket CSR finalize (1 block per bucket) ----------
__global__ void k_csr(const int* __restrict__ bucketBase, const int* __restrict__ sorted,
                      int* __restrict__ eidx, int* __restrict__ rowptr,
                      float* __restrict__ dis, int n) {
    __shared__ int pk[MAXB];
    __shared__ int deg[256];
    __shared__ int cur[256];
    __shared__ int wsum[4];
    int k = blockIdx.x;
    int base = bucketBase[k], end = bucketBase[k + 1];
    int m = end - base;
    int t = threadIdx.x;
    deg[t] = 0;
    __syncthreads();
    for (int j = t; j < m; j += 256) {
        int v = sorted[base + j];
        if (j < MAXB) pk[j] = v;
        atomicAdd(&deg[(v >> 17) & 255], 1);
    }
    __syncthreads();
    int dv = deg[t];
    int v2 = dv;
    int lane = t & 63, w = t >> 6;
    #pragma unroll
    for (int off = 1; off < 64; off <<= 1) {
        int u = __shfl_up(v2, off, 64);
        if (lane >= off) v2 += u;
    }
    if (lane == 63) wsum[w] = v2;
    __syncthreads();
    if (t == 0) {
        int acc = 0;
        #pragma unroll
        for (int i = 0; i < 4; ++i) { int x = wsum[i]; wsum[i] = acc; acc += x; }
    }
    __syncthreads();
    int excl = v2 - dv + wsum[w];
    int node = (k << 8) + t;
    if (node < n) {
        rowptr[node] = base + excl;
        dis[node] = rsqrtf((float)(dv + 1));   // +1 self-loop
    }
    cur[t] = excl;
    __syncthreads();
    for (int j = t; j < m; j += 256) {
        int v = (j < MAXB) ? pk[j] : sorted[base + j];
        int pos = atomicAdd(&cur[(v >> 17) & 255], 1);
        eidx[base + pos] = v & 0x1FFFF;
    }
}

// ---------- dense GEMM: HS2[n,DOUT/2] = pack_bf16x2((act(X[n,64]) @ W) * dis[row]) ----------
template<int DOUT, bool RELU_IN>
__global__ void k_gemm(const float* __restrict__ X, const float* __restrict__ W,
                       const float* __restrict__ dis, unsigned* __restrict__ HS2, int n) {
    __shared__ __align__(16) float Ws[64 * DOUT];
    for (int i = threadIdx.x; i < 64 * DOUT; i += blockDim.x) Ws[i] = W[i];
    __syncthreads();
    int row = blockIdx.x * blockDim.x + threadIdx.x;
    if (row >= n) return;
    float4 acc[DOUT / 4];
    #pragma unroll
    for (int j = 0; j < DOUT / 4; ++j) acc[j] = make_float4(0.f, 0.f, 0.f, 0.f);
    const float4* xr = (const float4*)(X + (size_t)row * 64);
    #pragma unroll
    for (int k4 = 0; k4 < 16; ++k4) {
        float4 xv = xr[k4];
        float xs[4];
        xs[0] = xv.x; xs[1] = xv.y; xs[2] = xv.z; xs[3] = xv.w;
        #pragma unroll
        for (int kk = 0; kk < 4; ++kk) {
            float xv1 = RELU_IN ? fmaxf(xs[kk], 0.f) : xs[kk];
            const float4* wr = (const float4*)&Ws[(k4 * 4 + kk) * DOUT];
            #pragma unroll
            for (int j = 0; j < DOUT / 4; ++j) {
                float4 wv = wr[j];
                acc[j].x += xv1 * wv.x;
                acc[j].y += xv1 * wv.y;
                acc[j].z += xv1 * wv.z;
                acc[j].w += xv1 * wv.w;
            }
        }
    }
    float ds = dis[row];
    uint2* hr = (uint2*)(HS2 + (size_t)row * (DOUT / 2));
    #pragma unroll
    for (int j = 0; j < DOUT / 4; ++j) {
        unsigned p0 = (unsigned)f2bf(acc[j].x * ds) | ((unsigned)f2bf(acc[j].y * ds) << 16);
        unsigned p1 = (unsigned)f2bf(acc[j].z * ds) | ((unsigned)f2bf(acc[j].w * ds) << 16);
        hr[j] = make_uint2(p0, p1);
    }
}

// ---------- gather: one wave per node; lane halves take alternating edges ----------
template<int DOUT, bool LSM>
__global__ void k_gather(const int* __restrict__ rowptr, const int* __restrict__ eidx,
                         const unsigned* __restrict__ hs2, const float* __restrict__ dis,
                         const float* __restrict__ b, float* __restrict__ out, int n) {
    const int C2 = DOUT / 2;
    int node = (blockIdx.x * blockDim.x + threadIdx.x) >> 6;
    int lane = threadIdx.x & 63;
    if (node >= n) return;
    int c2 = lane & 31, half = lane >> 5;
    bool act = c2 < C2;
    int s0 = rowptr[node];
    int d = rowptr[node + 1] - s0;
    const int* ep = eidx + s0;
    float a0 = 0.f, a1 = 0.f;
    if (half == 0 && act) {                                   // self-loop term
        unsigned v = hs2[(size_t)node * C2 + c2];
        a0 = bflo(v); a1 = bfhi(v);
    }
    int k = 0;
    for (; k + 8 <= d; k += 8) {
        int kb = k + half * 4;
        int e0 = ep[kb], e1 = ep[kb + 1], e2 = ep[kb + 2], e3 = ep[kb + 3];
        if (act) {
            unsigned v0 = hs2[(size_t)e0 * C2 + c2];
            unsigned v1 = hs2[(size_t)e1 * C2 + c2];
            unsigned v2 = hs2[(size_t)e2 * C2 + c2];
            unsigned v3 = hs2[(size_t)e3 * C2 + c2];
            a0 += bflo(v0) + bflo(v1) + bflo(v2) + bflo(v3);
            a1 += bfhi(v0) + bfhi(v1) + bfhi(v2) + bfhi(v3);
        }
    }
    for (; k + 2 <= d; k += 2) {
        int e0 = ep[k + half];
        if (act) {
            unsigned v = hs2[(size_t)e0 * C2 + c2];
            a0 += bflo(v); a1 += bfhi(v);
        }
    }
    if (k < d && half == 0 && act) {
        unsigned v = hs2[(size_t)ep[k] * C2 + c2];
        a0 += bflo(v); a1 += bfhi(v);
    }
    a0 += __shfl_xor(a0, 32, 64);
    a1 += __shfl_xor(a1, 32, 64);
    float ds = dis[node];
    float bb0 = act ? b[2 * c2] : 0.f;
    float bb1 = act ? b[2 * c2 + 1] : 0.f;
    a0 = a0 * ds + bb0;
    a1 = a1 * ds + bb1;
    if (!LSM) {
        if (half == 0 && act)
            *(float2*)(out + (size_t)node * DOUT + 2 * c2) = make_float2(a0, a1);
    } else {
        // fused log_softmax over DOUT channels (held 2-per-lane in lanes 0..C2-1, mirrored)
        float m = act ? fmaxf(a0, a1) : -INFINITY;
        #pragma unroll
        for (int off = 16; off >= 1; off >>= 1) m = fmaxf(m, __shfl_xor(m, off, 64));
        float s = act ? (__expf(a0 - m) + __expf(a1 - m)) : 0.f;
        #pragma unroll
        for (int off = 16; off >= 1; off >>= 1) s += __shfl_xor(s, off, 64);
        float ls = __logf(s);
        if (half == 0 && act)
            *(float2*)(out + (size_t)node * DOUT + 2 * c2) = make_float2(a0 - m - ls, a1 - m - ls);
    }
}

extern "C" void kernel_launch(void* const* d_in, const int* in_sizes, int n_in,
                              void* d_out, int out_size, void* d_ws, size_t ws_size,
                              hipStream_t stream) {
    const float* x  = (const float*)d_in[0];
    const int*   ei = (const int*)d_in[1];
    const float* W1 = (const float*)d_in[2];
    const float* b1 = (const float*)d_in[3];
    const float* W2 = (const float*)d_in[4];
    const float* b2 = (const float*)d_in[5];
    const float* W3 = (const float*)d_in[6];
    const float* b3 = (const float*)d_in[7];
    float* out = (float*)d_out;

    const int N = in_sizes[0] / 64;
    const int E = in_sizes[1] / 2;
    const int* src = ei;
    const int* dst = ei + E;
    const int NB = (N + 255) >> 8;          // buckets (<=512)
    const int CHUNK = (E + NBLK - 1) / NBLK;

    // workspace layout
    char* ws = (char*)d_ws;
    size_t off = 0;
    int*      rowptr     = (int*)(ws + off);      off = align256(off + (size_t)(N + 1) * 4);
    float*    dis        = (float*)(ws + off);    off = align256(off + (size_t)N * 4);
    int*      bucketBase = (int*)(ws + off);      off = align256(off + 2048 + 256);
    int*      eidx       = (int*)(ws + off);      off = align256(off + (size_t)E * 4);
    unsigned* hs2        = (unsigned*)(ws + off); off = align256(off + (size_t)N * 32 * 4);
    float*    agg        = (float*)(ws + off);    off = align256(off + (size_t)N * 64 * 4);
    // aliases (dead before hs2/agg first written):
    int*   blockHist  = (int*)hs2;                     // NBLK*NB ints (<=256KB)
    int*   blockOff   = (int*)hs2 + (size_t)NBLK * NB; // NBLK*NB ints
    int*   sorted     = (int*)agg;                     // E ints
    (void)ws_size; (void)n_in; (void)out_size;

    const int B = 256;
    auto cdiv = [](long a, long b) { return (int)((a + b - 1) / b); };

    // ---- CSR build (atomic-free bucketed counting sort) ----
    k_hist<<<NBLK, B, 0, stream>>>(dst, blockHist, E, NB, CHUNK);
    k_scan<<<1, 512, 0, stream>>>(blockHist, blockOff, bucketBase, rowptr, NBLK, NB, E, N);
    k_bucket<<<NBLK, B, 0, stream>>>(src, dst, blockOff, bucketBase, sorted, E, NB, CHUNK);
    k_csr<<<NB, B, 0, stream>>>(bucketBase, sorted, eidx, rowptr, dis, N);

    // ---- layer 1: x -> agg ----
    k_gemm<64, false><<<cdiv(N, B), B, 0, stream>>>(x, W1, dis, hs2, N);
    k_gather<64, false><<<cdiv((long)N * 64, B), B, 0, stream>>>(rowptr, eidx, hs2, dis, b1, agg, N);

    // ---- layer 2: relu(agg) -> agg ----
    k_gemm<64, true><<<cdiv(N, B), B, 0, stream>>>(agg, W2, dis, hs2, N);
    k_gather<64, false><<<cdiv((long)N * 64, B), B, 0, stream>>>(rowptr, eidx, hs2, dis, b2, agg, N);

    // ---- layer 3: relu(agg) -> out (40 ch) + fused log_softmax ----
    k_gemm<40, true><<<cdiv(N, B), B, 0, stream>>>(agg, W3, dis, hs2, N);
    k_gather<40, true><<<cdiv((long)N * 64, B), B, 0, stream>>>(rowptr, eidx, hs2, dis, b3, out, N);
}

// Round 5
// 304.460 us; speedup vs baseline: 12.8495x; 1.2881x over previous
//
#include <hip/hip_runtime.h>
#include <hip/hip_fp16.h>
#include <math.h>

// GCN 3-layer forward, CSR-gather formulation with packed-f16 message table.
// CSR built via atomic-free bucketed counting sort (bucket = dst>>8), fully parallel.
// out[i] = dis[i]*(hs[i] + sum_{src in N(i)} hs[src]) + b,  hs = (act(X)@W)*dis[row] (half2-packed)

static inline size_t align256(size_t x) { return (x + 255) & ~(size_t)255; }

#define NBLK 512          // blocks for hist/bucket passes
#define MAXB 6144         // max edges per bucket staged in LDS (mean 4092, sigma 64)

__device__ __forceinline__ __half2 u2h(unsigned u) { union { unsigned u; __half2 h; } t; t.u = u; return t.h; }
__device__ __forceinline__ unsigned h2u(__half2 h) { union { unsigned u; __half2 h; } t; t.h = h; return t.u; }

// exclusive scan of one value per thread across the block (<=512 threads, 64-lane waves)
template<int NW>
__device__ __forceinline__ int block_excl_scan(int v, int t, int* wsum) {
    int lane = t & 63, w = t >> 6;
    int incl = v;
    #pragma unroll
    for (int off = 1; off < 64; off <<= 1) {
        int u = __shfl_up(incl, off, 64);
        if (lane >= off) incl += u;
    }
    if (lane == 63) wsum[w] = incl;
    __syncthreads();
    if (t == 0) {
        int acc = 0;
        #pragma unroll
        for (int i = 0; i < NW; ++i) { int x = wsum[i]; wsum[i] = acc; acc += x; }
    }
    __syncthreads();
    return incl - v + wsum[w];
}

// ---------- pass 1: per-block bucket histogram (transposed store) ----------
__global__ void k_hist(const int* __restrict__ dst, int* __restrict__ bhT,
                       int e, int nb, int chunk) {
    __shared__ int h[512];
    for (int i = threadIdx.x; i < nb; i += blockDim.x) h[i] = 0;
    __syncthreads();
    int b0 = blockIdx.x * chunk, b1 = min(b0 + chunk, e);
    for (int i = b0 + threadIdx.x; i < b1; i += blockDim.x)
        atomicAdd(&h[dst[i] >> 8], 1);
    __syncthreads();
    for (int i = threadIdx.x; i < nb; i += blockDim.x)
        bhT[(size_t)i * NBLK + blockIdx.x] = h[i];     // [bucket][block]
}

// ---------- pass 2a: per-bucket scan over blocks (one block per bucket) ----------
__global__ void k_scanA(const int* __restrict__ bhT, int* __restrict__ boT,
                        int* __restrict__ total, int nb) {
    __shared__ int wsum[8];
    int k = blockIdx.x;       // bucket
    int t = threadIdx.x;      // source block (NBLK threads)
    int v = bhT[(size_t)k * NBLK + t];
    int excl = block_excl_scan<8>(v, t, wsum);
    boT[(size_t)t * nb + k] = excl;                    // [block][bucket] for k_bucket
    if (t == NBLK - 1) total[k] = excl + v;
}

// ---------- pass 2b: bucket bases (1 block) ----------
__global__ void k_scanB(const int* __restrict__ total, int* __restrict__ bucketBase,
                        int* __restrict__ rowptr, int nb, int e, int n) {
    __shared__ int wsum[8];
    int t = threadIdx.x;
    int v = (t < nb) ? total[t] : 0;
    int excl = block_excl_scan<8>(v, t, wsum);
    if (t < nb) bucketBase[t] = excl;
    if (t == 0) { bucketBase[nb] = e; rowptr[n] = e; }
}

// ---------- pass 3: scatter edges into bucket-sorted packed array ----------
__global__ void k_bucket(const int* __restrict__ src, const int* __restrict__ dst,
                         const int* __restrict__ boT, const int* __restrict__ bucketBase,
                         int* __restrict__ sorted, int e, int nb, int chunk) {
    __shared__ int cur[512];
    const int* bo = boT + (size_t)blockIdx.x * nb;
    for (int i = threadIdx.x; i < nb; i += blockDim.x)
        cur[i] = bo[i] + bucketBase[i];
    __syncthreads();
    int b0 = blockIdx.x * chunk, b1 = min(b0 + chunk, e);
    for (int i = b0 + threadIdx.x; i < b1; i += blockDim.x) {
        int d = dst[i];
        int pos = atomicAdd(&cur[d >> 8], 1);
        sorted[pos] = src[i] | ((d & 255) << 17);   // src < 2^17, dlow 8 bits
    }
}

// ---------- pass 4: per-bucket CSR finalize (1 block per bucket) ----------
__global__ void k_csr(const int* __restrict__ bucketBase, const int* __restrict__ sorted,
                      int* __restrict__ eidx, int* __restrict__ rowptr,
                      float* __restrict__ dis, int n) {
    __shared__ int pk[MAXB];
    __shared__ int pk2[MAXB];
    __shared__ int deg[256];
    __shared__ int cur[256];
    __shared__ int wsum[4];
    int k = blockIdx.x;
    int base = bucketBase[k], end = bucketBase[k + 1];
    int m = end - base;
    int t = threadIdx.x;
    deg[t] = 0;
    __syncthreads();
    for (int j = t; j < m; j += 256) {
        int v = sorted[base + j];
        if (j < MAXB) pk[j] = v;
        atomicAdd(&deg[(v >> 17) & 255], 1);
    }
    __syncthreads();
    int dv = deg[t];
    int excl = block_excl_scan<4>(dv, t, wsum);
    int node = (k << 8) + t;
    if (node < n) {
        rowptr[node] = base + excl;
        dis[node] = rsqrtf((float)(dv + 1));   // +1 self-loop
    }
    cur[t] = excl;
    __syncthreads();
    for (int j = t; j < m; j += 256) {
        int v = (j < MAXB) ? pk[j] : sorted[base + j];
        int pos = atomicAdd(&cur[(v >> 17) & 255], 1);
        int sv = v & 0x1FFFF;
        if (pos < MAXB) pk2[pos] = sv;
        else eidx[base + pos] = sv;            // overflow straight to global
    }
    __syncthreads();
    int mm = min(m, MAXB);
    for (int j = t; j < mm; j += 256)
        eidx[base + j] = pk2[j];               // coalesced dump
}

// ---------- dense GEMM: HS2[n] = pack_f16x2((act(X[n,64]) @ W) * dis[row]) ----------
template<int DOUT, bool RELU_IN>
__global__ void k_gemm(const float* __restrict__ X, const float* __restrict__ W,
                       const float* __restrict__ dis, unsigned* __restrict__ HS2, int n) {
    __shared__ __align__(16) float Ws[64 * DOUT];
    for (int i = threadIdx.x; i < 64 * DOUT; i += blockDim.x) Ws[i] = W[i];
    __syncthreads();
    int row = blockIdx.x * blockDim.x + threadIdx.x;
    if (row >= n) return;
    float4 acc[DOUT / 4];
    #pragma unroll
    for (int j = 0; j < DOUT / 4; ++j) acc[j] = make_float4(0.f, 0.f, 0.f, 0.f);
    const float4* xr = (const float4*)(X + (size_t)row * 64);
    #pragma unroll
    for (int k4 = 0; k4 < 16; ++k4) {
        float4 xv = xr[k4];
        float xs[4];
        xs[0] = xv.x; xs[1] = xv.y; xs[2] = xv.z; xs[3] = xv.w;
        #pragma unroll
        for (int kk = 0; kk < 4; ++kk) {
            float xv1 = RELU_IN ? fmaxf(xs[kk], 0.f) : xs[kk];
            const float4* wr = (const float4*)&Ws[(k4 * 4 + kk) * DOUT];
            #pragma unroll
            for (int j = 0; j < DOUT / 4; ++j) {
                float4 wv = wr[j];
                acc[j].x += xv1 * wv.x;
                acc[j].y += xv1 * wv.y;
                acc[j].z += xv1 * wv.z;
                acc[j].w += xv1 * wv.w;
            }
        }
    }
    float ds = dis[row];
    uint2* hr = (uint2*)(HS2 + (size_t)row * (DOUT / 2));
    #pragma unroll
    for (int j = 0; j < DOUT / 4; ++j) {
        __half2 p0 = __floats2half2_rn(acc[j].x * ds, acc[j].y * ds);
        __half2 p1 = __floats2half2_rn(acc[j].z * ds, acc[j].w * ds);
        hr[j] = make_uint2(h2u(p0), h2u(p1));
    }
}

// ---------- gather: one wave per node; lane = 16*q + c; q = edge slot, c = channel quad ----------
template<int DOUT, bool LSM>
__global__ void k_gather(const int* __restrict__ rowptr, const int* __restrict__ eidx,
                         const uint2* __restrict__ hs2, const float* __restrict__ dis,
                         const float* __restrict__ b, float* __restrict__ out, int n) {
    const int C4 = DOUT / 4;                   // uint2 (4-channel) slots per row
    int node = (blockIdx.x * blockDim.x + threadIdx.x) >> 6;
    int lane = threadIdx.x & 63;
    if (node >= n) return;
    int c = lane & 15, q = lane >> 4;
    bool act = c < C4;
    int s0 = rowptr[node];
    int d = rowptr[node + 1] - s0;
    const int* ep = eidx + s0;
    __half2 acc0 = u2h(0u), acc1 = u2h(0u);
    if (q == 0) {                               // self-loop term
        uint2 v = hs2[(size_t)node * C4 + c];
        acc0 = u2h(v.x); acc1 = u2h(v.y);
    }
    int k = 0;
    for (; k + 8 <= d; k += 8) {
        int e0 = ep[k + q], e1 = ep[k + 4 + q];
        uint2 v0 = hs2[(size_t)e0 * C4 + c];
        uint2 v1 = hs2[(size_t)e1 * C4 + c];
        acc0 = __hadd2(acc0, u2h(v0.x)); acc1 = __hadd2(acc1, u2h(v0.y));
        acc0 = __hadd2(acc0, u2h(v1.x)); acc1 = __hadd2(acc1, u2h(v1.y));
    }
    {
        int i0 = k + q, i1 = k + 4 + q;
        if (i0 < d) {
            uint2 v = hs2[(size_t)ep[i0] * C4 + c];
            acc0 = __hadd2(acc0, u2h(v.x)); acc1 = __hadd2(acc1, u2h(v.y));
        }
        if (i1 < d) {
            uint2 v = hs2[(size_t)ep[i1] * C4 + c];
            acc0 = __hadd2(acc0, u2h(v.x)); acc1 = __hadd2(acc1, u2h(v.y));
        }
    }
    // reduce across the 4 edge slots (lanes c, c+16, c+32, c+48)
    unsigned a0 = h2u(acc0), a1 = h2u(acc1);
    a0 = h2u(__hadd2(u2h(a0), u2h(__shfl_xor(a0, 16, 64))));
    a1 = h2u(__hadd2(u2h(a1), u2h(__shfl_xor(a1, 16, 64))));
    a0 = h2u(__hadd2(u2h(a0), u2h(__shfl_xor(a0, 32, 64))));
    a1 = h2u(__hadd2(u2h(a1), u2h(__shfl_xor(a1, 32, 64))));
    float2 f0 = __half22float2(u2h(a0));
    float2 f1 = __half22float2(u2h(a1));
    float ds = dis[node];
    float4 bb = make_float4(0.f, 0.f, 0.f, 0.f);
    if (act) bb = *(const float4*)(b + 4 * c);
    float v0 = f0.x * ds + bb.x, v1 = f0.y * ds + bb.y;
    float v2 = f1.x * ds + bb.z, v3 = f1.y * ds + bb.w;
    if (!LSM) {
        if (q == 0 && act)
            *(float4*)(out + (size_t)node * DOUT + 4 * c) = make_float4(v0, v1, v2, v3);
    } else {
        float m = act ? fmaxf(fmaxf(v0, v1), fmaxf(v2, v3)) : -INFINITY;
        #pragma unroll
        for (int off = 8; off >= 1; off >>= 1) m = fmaxf(m, __shfl_xor(m, off, 64));
        float s = act ? (__expf(v0 - m) + __expf(v1 - m) + __expf(v2 - m) + __expf(v3 - m)) : 0.f;
        #pragma unroll
        for (int off = 8; off >= 1; off >>= 1) s += __shfl_xor(s, off, 64);
        float ls = __logf(s);
        if (q == 0 && act)
            *(float4*)(out + (size_t)node * DOUT + 4 * c) =
                make_float4(v0 - m - ls, v1 - m - ls, v2 - m - ls, v3 - m - ls);
    }
}

extern "C" void kernel_launch(void* const* d_in, const int* in_sizes, int n_in,
                              void* d_out, int out_size, void* d_ws, size_t ws_size,
                              hipStream_t stream) {
    const float* x  = (const float*)d_in[0];
    const int*   ei = (const int*)d_in[1];
    const float* W1 = (const float*)d_in[2];
    const float* b1 = (const float*)d_in[3];
    const float* W2 = (const float*)d_in[4];
    const float* b2 = (const float*)d_in[5];
    const float* W3 = (const float*)d_in[6];
    const float* b3 = (const float*)d_in[7];
    float* out = (float*)d_out;

    const int N = in_sizes[0] / 64;
    const int E = in_sizes[1] / 2;
    const int* src = ei;
    const int* dst = ei + E;
    const int NB = (N + 255) >> 8;          // buckets (<=512)
    const int CHUNK = (E + NBLK - 1) / NBLK;

    // workspace layout
    char* ws = (char*)d_ws;
    size_t off = 0;
    int*      rowptr     = (int*)(ws + off);      off = align256(off + (size_t)(N + 1) * 4);
    float*    dis        = (float*)(ws + off);    off = align256(off + (size_t)N * 4);
    int*      bucketBase = (int*)(ws + off);      off = align256(off + 2048 + 256);
    int*      eidx       = (int*)(ws + off);      off = align256(off + (size_t)E * 4);
    unsigned* hs2        = (unsigned*)(ws + off); off = align256(off + (size_t)N * 32 * 4);
    float*    agg        = (float*)(ws + off);    off = align256(off + (size_t)N * 64 * 4);
    // aliases (dead before hs2/agg first written):
    int* bhT    = (int*)hs2;                          // [NB][NBLK]  (~800KB)
    int* boT    = bhT + (size_t)NB * NBLK;            // [NBLK][NB]
    int* total  = boT + (size_t)NB * NBLK;            // [NB]
    int* sorted = (int*)agg;                          // E ints
    (void)ws_size; (void)n_in; (void)out_size;

    const int B = 256;
    auto cdiv = [](long a, long b) { return (int)((a + b - 1) / b); };

    // ---- CSR build (atomic-free bucketed counting sort, fully parallel) ----
    k_hist<<<NBLK, B, 0, stream>>>(dst, bhT, E, NB, CHUNK);
    k_scanA<<<NB, NBLK, 0, stream>>>(bhT, boT, total, NB);
    k_scanB<<<1, 512, 0, stream>>>(total, bucketBase, rowptr, NB, E, N);
    k_bucket<<<NBLK, B, 0, stream>>>(src, dst, boT, bucketBase, sorted, E, NB, CHUNK);
    k_csr<<<NB, B, 0, stream>>>(bucketBase, sorted, eidx, rowptr, dis, N);

    // ---- layer 1: x -> agg ----
    k_gemm<64, false><<<cdiv(N, B), B, 0, stream>>>(x, W1, dis, hs2, N);
    k_gather<64, false><<<cdiv((long)N * 64, B), B, 0, stream>>>(rowptr, eidx, (const uint2*)hs2, dis, b1, agg, N);

    // ---- layer 2: relu(agg) -> agg ----
    k_gemm<64, true><<<cdiv(N, B), B, 0, stream>>>(agg, W2, dis, hs2, N);
    k_gather<64, false><<<cdiv((long)N * 64, B), B, 0, stream>>>(rowptr, eidx, (const uint2*)hs2, dis, b2, agg, N);

    // ---- layer 3: relu(agg) -> out (40 ch) + fused log_softmax ----
    k_gemm<40, true><<<cdiv(N, B), B, 0, stream>>>(agg, W3, dis, hs2, N);
    k_gather<40, true><<<cdiv((long)N * 64, B), B, 0, stream>>>(rowptr, eidx, (const uint2*)hs2, dis, b3, out, N);
}